// Round 1
// baseline (1805.537 us; speedup 1.0000x reference)
//
#include <hip/hip_runtime.h>

#define N_NODES 16384
#define IN_F    128
#define H1      15      // psi hidden (padded to 16 in LDS)
#define PSI_F   16
#define ZF      (IN_F + PSI_F)   // 144
#define H2      25      // fi hidden (padded to 28 in LDS)
#define OUT_F   128

// ---- agg kernel tiling ----
#define AGG_TB   256                 // threads per block
#define AGG_CPT  2                   // columns per thread (int2 load)
#define AGG_CPB  (AGG_TB * AGG_CPT)  // 512 columns per block
#define AGG_CB   (N_NODES / AGG_CPB) // 32 column blocks
#define AGG_RS   32                  // row slices
#define AGG_RPB  (N_NODES / AGG_RS)  // 512 rows per block

// ===================== psi MLP: h = relu(relu(x W1 + b1) W2 + b2) =====================
__global__ __launch_bounds__(64) void psi_kernel(
    const float* __restrict__ nodes,
    const float* __restrict__ w1, const float* __restrict__ b1,
    const float* __restrict__ w2, const float* __restrict__ b2,
    float* __restrict__ h) {
  __shared__ float sw1[IN_F * 16];   // [128][16], col 15 zero-padded
  __shared__ float sw2[16 * PSI_F];  // [16][16], row 15 zero-padded
  __shared__ float sb1[16];
  __shared__ float sb2[PSI_F];
  const int t = threadIdx.x;
  for (int i = t; i < IN_F * 16; i += 64) {
    int k = i >> 4, j = i & 15;
    sw1[i] = (j < H1) ? w1[k * H1 + j] : 0.0f;
  }
  for (int i = t; i < 16 * PSI_F; i += 64) {
    int j = i >> 4, j2 = i & 15;
    sw2[i] = (j < H1) ? w2[j * PSI_F + j2] : 0.0f;
  }
  if (t < 16)   sb1[t] = (t < H1) ? b1[t] : 0.0f;
  if (t < PSI_F) sb2[t] = b2[t];
  __syncthreads();

  const int node = blockIdx.x * 64 + t;
  const float4* __restrict__ row = (const float4*)(nodes + (size_t)node * IN_F);
  const float4* __restrict__ sw1v = (const float4*)sw1;
  const float4* __restrict__ sw2v = (const float4*)sw2;

  float a1[16];
#pragma unroll
  for (int j = 0; j < 16; ++j) a1[j] = sb1[j];

#pragma unroll 4
  for (int k4 = 0; k4 < IN_F / 4; ++k4) {
    float4 x = row[k4];
    float xs[4] = {x.x, x.y, x.z, x.w};
#pragma unroll
    for (int kk = 0; kk < 4; ++kk) {
#pragma unroll
      for (int j4 = 0; j4 < 4; ++j4) {
        float4 w = sw1v[(k4 * 4 + kk) * 4 + j4];
        a1[j4 * 4 + 0] = fmaf(xs[kk], w.x, a1[j4 * 4 + 0]);
        a1[j4 * 4 + 1] = fmaf(xs[kk], w.y, a1[j4 * 4 + 1]);
        a1[j4 * 4 + 2] = fmaf(xs[kk], w.z, a1[j4 * 4 + 2]);
        a1[j4 * 4 + 3] = fmaf(xs[kk], w.w, a1[j4 * 4 + 3]);
      }
    }
  }

  float a2[PSI_F];
#pragma unroll
  for (int j2 = 0; j2 < PSI_F; ++j2) a2[j2] = sb2[j2];
#pragma unroll
  for (int j = 0; j < 16; ++j) {
    float v = fmaxf(a1[j], 0.0f);   // row 15 of sw2 is zero, padded lane harmless
#pragma unroll
    for (int j4 = 0; j4 < 4; ++j4) {
      float4 w = sw2v[j * 4 + j4];
      a2[j4 * 4 + 0] = fmaf(v, w.x, a2[j4 * 4 + 0]);
      a2[j4 * 4 + 1] = fmaf(v, w.y, a2[j4 * 4 + 1]);
      a2[j4 * 4 + 2] = fmaf(v, w.z, a2[j4 * 4 + 2]);
      a2[j4 * 4 + 3] = fmaf(v, w.w, a2[j4 * 4 + 3]);
    }
  }

  float4* __restrict__ hp = (float4*)(h + (size_t)node * PSI_F);
#pragma unroll
  for (int j4 = 0; j4 < 4; ++j4) {
    hp[j4] = make_float4(fmaxf(a2[j4 * 4 + 0], 0.0f), fmaxf(a2[j4 * 4 + 1], 0.0f),
                         fmaxf(a2[j4 * 4 + 2], 0.0f), fmaxf(a2[j4 * 4 + 3], 0.0f));
  }
}

// ===================== aggregation: acc[i][k] += sum_j A[j][i] h[j][k]; cnt[i] += sum_j A[j][i]
__global__ __launch_bounds__(256) void agg_kernel(
    const int* __restrict__ A, const float* __restrict__ h,
    float* __restrict__ acc, float* __restrict__ cnt) {
  const int cb = blockIdx.x % AGG_CB;
  const int rs = blockIdx.x / AGG_CB;
  const int c0 = cb * AGG_CPB + threadIdx.x * AGG_CPT;
  const int r0 = rs * AGG_RPB;

  float s0[PSI_F], s1[PSI_F];
#pragma unroll
  for (int k = 0; k < PSI_F; ++k) { s0[k] = 0.0f; s1[k] = 0.0f; }
  float n0 = 0.0f, n1 = 0.0f;

  const int* __restrict__ ap = A + (size_t)r0 * N_NODES + c0;
  const float* __restrict__ hp = h + (size_t)r0 * PSI_F;

#pragma unroll 2
  for (int r = 0; r < AGG_RPB; ++r) {
    int2 a = *(const int2*)ap;
    float a0 = (float)a.x;
    float a1 = (float)a.y;
#pragma unroll
    for (int k = 0; k < PSI_F; ++k) {
      float hv = hp[k];
      s0[k] = fmaf(a0, hv, s0[k]);
      s1[k] = fmaf(a1, hv, s1[k]);
    }
    n0 += a0; n1 += a1;
    ap += N_NODES;
    hp += PSI_F;
  }

  float* accp = acc + (size_t)c0 * PSI_F;
#pragma unroll
  for (int k = 0; k < PSI_F; ++k) {
    atomicAdd(accp + k, s0[k]);
    atomicAdd(accp + PSI_F + k, s1[k]);
  }
  atomicAdd(cnt + c0, n0);
  atomicAdd(cnt + c0 + 1, n1);
}

// ===================== fi MLP: out = relu(relu([x, psi] W1 + b1) W2 + b2) =====================
__global__ __launch_bounds__(64) void fi_kernel(
    const float* __restrict__ nodes, const float* __restrict__ acc, const float* __restrict__ cnt,
    const float* __restrict__ w1, const float* __restrict__ b1,
    const float* __restrict__ w2, const float* __restrict__ b2,
    float* __restrict__ out) {
  __shared__ float sw1[ZF * 28];     // [144][28], cols 25..27 zero
  __shared__ float sw2[H2 * OUT_F];  // [25][128]
  __shared__ float sb1[28];
  __shared__ float sb2[OUT_F];
  const int t = threadIdx.x;
  for (int i = t; i < ZF * 28; i += 64) {
    int k = i / 28, j = i % 28;
    sw1[i] = (j < H2) ? w1[k * H2 + j] : 0.0f;
  }
  for (int i = t; i < H2 * OUT_F; i += 64) sw2[i] = w2[i];
  if (t < 28) sb1[t] = (t < H2) ? b1[t] : 0.0f;
  for (int i = t; i < OUT_F; i += 64) sb2[i] = b2[i];
  __syncthreads();

  const int node = blockIdx.x * 64 + t;
  const float4* __restrict__ sw1v = (const float4*)sw1;
  const float4* __restrict__ sw2v = (const float4*)sw2;

  float g[28];
#pragma unroll
  for (int j = 0; j < 28; ++j) g[j] = sb1[j];

  const float4* __restrict__ nrow = (const float4*)(nodes + (size_t)node * IN_F);
#pragma unroll 2
  for (int k4 = 0; k4 < IN_F / 4; ++k4) {
    float4 x = nrow[k4];
    float xs[4] = {x.x, x.y, x.z, x.w};
#pragma unroll
    for (int kk = 0; kk < 4; ++kk) {
      const int k = k4 * 4 + kk;
#pragma unroll
      for (int j4 = 0; j4 < 7; ++j4) {
        float4 w = sw1v[k * 7 + j4];
        g[j4 * 4 + 0] = fmaf(xs[kk], w.x, g[j4 * 4 + 0]);
        g[j4 * 4 + 1] = fmaf(xs[kk], w.y, g[j4 * 4 + 1]);
        g[j4 * 4 + 2] = fmaf(xs[kk], w.z, g[j4 * 4 + 2]);
        g[j4 * 4 + 3] = fmaf(xs[kk], w.w, g[j4 * 4 + 3]);
      }
    }
  }

  const float invc = 1.0f / cnt[node];
  const float4* __restrict__ prow = (const float4*)(acc + (size_t)node * PSI_F);
#pragma unroll
  for (int k4 = 0; k4 < PSI_F / 4; ++k4) {
    float4 p = prow[k4];
    float xs[4] = {p.x * invc, p.y * invc, p.z * invc, p.w * invc};
#pragma unroll
    for (int kk = 0; kk < 4; ++kk) {
      const int k = IN_F + k4 * 4 + kk;
#pragma unroll
      for (int j4 = 0; j4 < 7; ++j4) {
        float4 w = sw1v[k * 7 + j4];
        g[j4 * 4 + 0] = fmaf(xs[kk], w.x, g[j4 * 4 + 0]);
        g[j4 * 4 + 1] = fmaf(xs[kk], w.y, g[j4 * 4 + 1]);
        g[j4 * 4 + 2] = fmaf(xs[kk], w.z, g[j4 * 4 + 2]);
        g[j4 * 4 + 3] = fmaf(xs[kk], w.w, g[j4 * 4 + 3]);
      }
    }
  }

#pragma unroll
  for (int j = 0; j < H2; ++j) g[j] = fmaxf(g[j], 0.0f);

  float4* __restrict__ op = (float4*)(out + (size_t)node * OUT_F);
#pragma unroll
  for (int oc = 0; oc < 4; ++oc) {
    float o[32];
#pragma unroll
    for (int i = 0; i < 32; ++i) o[i] = sb2[oc * 32 + i];
#pragma unroll
    for (int j = 0; j < H2; ++j) {
      float gv = g[j];
#pragma unroll
      for (int o4 = 0; o4 < 8; ++o4) {
        float4 w = sw2v[(j * OUT_F + oc * 32) / 4 + o4];
        o[o4 * 4 + 0] = fmaf(gv, w.x, o[o4 * 4 + 0]);
        o[o4 * 4 + 1] = fmaf(gv, w.y, o[o4 * 4 + 1]);
        o[o4 * 4 + 2] = fmaf(gv, w.z, o[o4 * 4 + 2]);
        o[o4 * 4 + 3] = fmaf(gv, w.w, o[o4 * 4 + 3]);
      }
    }
#pragma unroll
    for (int o4 = 0; o4 < 8; ++o4) {
      op[oc * 8 + o4] = make_float4(fmaxf(o[o4 * 4 + 0], 0.0f), fmaxf(o[o4 * 4 + 1], 0.0f),
                                    fmaxf(o[o4 * 4 + 2], 0.0f), fmaxf(o[o4 * 4 + 3], 0.0f));
    }
  }
}

extern "C" void kernel_launch(void* const* d_in, const int* in_sizes, int n_in,
                              void* d_out, int out_size, void* d_ws, size_t ws_size,
                              hipStream_t stream) {
  const float* nodes  = (const float*)d_in[0];
  const int*   A      = (const int*)d_in[1];
  const float* psi_w1 = (const float*)d_in[2];
  const float* psi_b1 = (const float*)d_in[3];
  const float* psi_w2 = (const float*)d_in[4];
  const float* psi_b2 = (const float*)d_in[5];
  const float* fi_w1  = (const float*)d_in[6];
  const float* fi_b1  = (const float*)d_in[7];
  const float* fi_w2  = (const float*)d_in[8];
  const float* fi_b2  = (const float*)d_in[9];
  float* out = (float*)d_out;

  // workspace layout: h [N][16] | acc [N][16] | cnt [N]
  float* h   = (float*)d_ws;
  float* acc = h + (size_t)N_NODES * PSI_F;
  float* cnt = acc + (size_t)N_NODES * PSI_F;

  // zero the accumulators (ws is poisoned 0xAA before every launch)
  hipMemsetAsync(acc, 0, (size_t)N_NODES * (PSI_F + 1) * sizeof(float), stream);

  psi_kernel<<<N_NODES / 64, 64, 0, stream>>>(nodes, psi_w1, psi_b1, psi_w2, psi_b2, h);
  agg_kernel<<<AGG_CB * AGG_RS, AGG_TB, 0, stream>>>(A, h, acc, cnt);
  fi_kernel<<<N_NODES / 64, 64, 0, stream>>>(nodes, acc, cnt, fi_w1, fi_b1, fi_w2, fi_b2, out);
}

// Round 2
// 1503.917 us; speedup vs baseline: 1.2006x; 1.2006x over previous
//
#include <hip/hip_runtime.h>

#define N_NODES 16384
#define IN_F    128
#define H1      15      // psi hidden (padded to 16 in LDS)
#define PSI_F   16
#define ZF      (IN_F + PSI_F)   // 144
#define H2      25      // fi hidden (padded to 28 in LDS)
#define OUT_F   128

// ---- agg kernel tiling ----
#define AGG_TB   256                 // threads per block
#define AGG_CPT  4                   // columns per thread (int4 load)
#define AGG_CPB  (AGG_TB * AGG_CPT)  // 1024 columns per block
#define AGG_CB   (N_NODES / AGG_CPB) // 16 column blocks
#define AGG_RS   64                  // row slices
#define AGG_RPB  (N_NODES / AGG_RS)  // 256 rows per block

typedef int   v4i __attribute__((ext_vector_type(4)));
typedef float v4f __attribute__((ext_vector_type(4)));

// ===================== psi MLP: h = relu(relu(x W1 + b1) W2 + b2) =====================
__global__ __launch_bounds__(64) void psi_kernel(
    const float* __restrict__ nodes,
    const float* __restrict__ w1, const float* __restrict__ b1,
    const float* __restrict__ w2, const float* __restrict__ b2,
    float* __restrict__ h) {
  __shared__ float sw1[IN_F * 16];   // [128][16], col 15 zero-padded
  __shared__ float sw2[16 * PSI_F];  // [16][16], row 15 zero-padded
  __shared__ float sb1[16];
  __shared__ float sb2[PSI_F];
  const int t = threadIdx.x;
  for (int i = t; i < IN_F * 16; i += 64) {
    int k = i >> 4, j = i & 15;
    sw1[i] = (j < H1) ? w1[k * H1 + j] : 0.0f;
  }
  for (int i = t; i < 16 * PSI_F; i += 64) {
    int j = i >> 4, j2 = i & 15;
    sw2[i] = (j < H1) ? w2[j * PSI_F + j2] : 0.0f;
  }
  if (t < 16)   sb1[t] = (t < H1) ? b1[t] : 0.0f;
  if (t < PSI_F) sb2[t] = b2[t];
  __syncthreads();

  const int node = blockIdx.x * 64 + t;
  const float4* __restrict__ row = (const float4*)(nodes + (size_t)node * IN_F);
  const float4* __restrict__ sw1v = (const float4*)sw1;
  const float4* __restrict__ sw2v = (const float4*)sw2;

  float a1[16];
#pragma unroll
  for (int j = 0; j < 16; ++j) a1[j] = sb1[j];

#pragma unroll 4
  for (int k4 = 0; k4 < IN_F / 4; ++k4) {
    float4 x = row[k4];
    float xs[4] = {x.x, x.y, x.z, x.w};
#pragma unroll
    for (int kk = 0; kk < 4; ++kk) {
#pragma unroll
      for (int j4 = 0; j4 < 4; ++j4) {
        float4 w = sw1v[(k4 * 4 + kk) * 4 + j4];
        a1[j4 * 4 + 0] = fmaf(xs[kk], w.x, a1[j4 * 4 + 0]);
        a1[j4 * 4 + 1] = fmaf(xs[kk], w.y, a1[j4 * 4 + 1]);
        a1[j4 * 4 + 2] = fmaf(xs[kk], w.z, a1[j4 * 4 + 2]);
        a1[j4 * 4 + 3] = fmaf(xs[kk], w.w, a1[j4 * 4 + 3]);
      }
    }
  }

  float a2[PSI_F];
#pragma unroll
  for (int j2 = 0; j2 < PSI_F; ++j2) a2[j2] = sb2[j2];
#pragma unroll
  for (int j = 0; j < 16; ++j) {
    float v = fmaxf(a1[j], 0.0f);   // row 15 of sw2 is zero, padded lane harmless
#pragma unroll
    for (int j4 = 0; j4 < 4; ++j4) {
      float4 w = sw2v[j * 4 + j4];
      a2[j4 * 4 + 0] = fmaf(v, w.x, a2[j4 * 4 + 0]);
      a2[j4 * 4 + 1] = fmaf(v, w.y, a2[j4 * 4 + 1]);
      a2[j4 * 4 + 2] = fmaf(v, w.z, a2[j4 * 4 + 2]);
      a2[j4 * 4 + 3] = fmaf(v, w.w, a2[j4 * 4 + 3]);
    }
  }

  float4* __restrict__ hp = (float4*)(h + (size_t)node * PSI_F);
#pragma unroll
  for (int j4 = 0; j4 < 4; ++j4) {
    hp[j4] = make_float4(fmaxf(a2[j4 * 4 + 0], 0.0f), fmaxf(a2[j4 * 4 + 1], 0.0f),
                         fmaxf(a2[j4 * 4 + 2], 0.0f), fmaxf(a2[j4 * 4 + 3], 0.0f));
  }
}

// ===================== aggregation partials =====================
// pacc[rs][c][k] = sum_{r in slice rs} A[r][c] * h[r][k]
// pcnt[rs][c]    = sum_{r in slice rs} A[r][c]
__global__ __launch_bounds__(256) void agg_kernel(
    const int* __restrict__ A, const float* __restrict__ h,
    float* __restrict__ pacc, float* __restrict__ pcnt) {
  __shared__ float sh[AGG_RPB * PSI_F];   // 16 KB: h slice for this block's rows
  const int cb = blockIdx.x % AGG_CB;
  const int rs = blockIdx.x / AGG_CB;
  const int r0 = rs * AGG_RPB;

  // stage h[r0 .. r0+255][0..15] into LDS
  {
    const float4* __restrict__ hsrc = (const float4*)(h + (size_t)r0 * PSI_F);
    float4* __restrict__ shv = (float4*)sh;
    for (int i = threadIdx.x; i < AGG_RPB * PSI_F / 4; i += AGG_TB) shv[i] = hsrc[i];
  }
  __syncthreads();

  const int c0 = cb * AGG_CPB + threadIdx.x * AGG_CPT;

  float s[AGG_CPT][PSI_F];
  float n[AGG_CPT];
#pragma unroll
  for (int c = 0; c < AGG_CPT; ++c) {
    n[c] = 0.0f;
#pragma unroll
    for (int k = 0; k < PSI_F; ++k) s[c][k] = 0.0f;
  }

  const v4i* __restrict__ ap = (const v4i*)(A + (size_t)r0 * N_NODES + c0);
  const float4* __restrict__ shv = (const float4*)sh;

#pragma unroll 4
  for (int r = 0; r < AGG_RPB; ++r) {
    v4i av = __builtin_nontemporal_load(ap);
    ap += N_NODES / 4;
    float a[AGG_CPT] = {(float)av[0], (float)av[1], (float)av[2], (float)av[3]};
    float4 hv[4] = {shv[r * 4 + 0], shv[r * 4 + 1], shv[r * 4 + 2], shv[r * 4 + 3]};
#pragma unroll
    for (int c = 0; c < AGG_CPT; ++c) {
#pragma unroll
      for (int q = 0; q < 4; ++q) {
        s[c][q * 4 + 0] = fmaf(a[c], hv[q].x, s[c][q * 4 + 0]);
        s[c][q * 4 + 1] = fmaf(a[c], hv[q].y, s[c][q * 4 + 1]);
        s[c][q * 4 + 2] = fmaf(a[c], hv[q].z, s[c][q * 4 + 2]);
        s[c][q * 4 + 3] = fmaf(a[c], hv[q].w, s[c][q * 4 + 3]);
      }
      n[c] += a[c];
    }
  }

  // write partials (contiguous 256 B per thread, coalesced across wave)
  float* __restrict__ pa = pacc + ((size_t)rs * N_NODES + c0) * PSI_F;
#pragma unroll
  for (int c = 0; c < AGG_CPT; ++c) {
#pragma unroll
    for (int q = 0; q < 4; ++q) {
      v4f v = {s[c][q * 4 + 0], s[c][q * 4 + 1], s[c][q * 4 + 2], s[c][q * 4 + 3]};
      __builtin_nontemporal_store(v, (v4f*)(pa + c * PSI_F + q * 4));
    }
  }
  v4f nv = {n[0], n[1], n[2], n[3]};
  __builtin_nontemporal_store(nv, (v4f*)(pcnt + (size_t)rs * N_NODES + c0));
}

// ===================== reduce partials: acc[node][k], cnt[node] =====================
__global__ __launch_bounds__(256) void reduce_kernel(
    const float* __restrict__ pacc, const float* __restrict__ pcnt,
    float* __restrict__ acc, float* __restrict__ cnt) {
  const int idx = blockIdx.x * 256 + threadIdx.x;   // over N*PSI_F = 262144
  float s = 0.0f;
  const float* __restrict__ p = pacc + idx;
#pragma unroll 8
  for (int rs = 0; rs < AGG_RS; ++rs) {
    s += *p;
    p += (size_t)N_NODES * PSI_F;
  }
  acc[idx] = s;
  if (idx < N_NODES) {
    float c = 0.0f;
    const float* __restrict__ q = pcnt + idx;
#pragma unroll 8
    for (int rs = 0; rs < AGG_RS; ++rs) {
      c += *q;
      q += N_NODES;
    }
    cnt[idx] = c;
  }
}

// ===================== fi MLP: out = relu(relu([x, psi] W1 + b1) W2 + b2) =====================
__global__ __launch_bounds__(64) void fi_kernel(
    const float* __restrict__ nodes, const float* __restrict__ acc, const float* __restrict__ cnt,
    const float* __restrict__ w1, const float* __restrict__ b1,
    const float* __restrict__ w2, const float* __restrict__ b2,
    float* __restrict__ out) {
  __shared__ float sw1[ZF * 28];     // [144][28], cols 25..27 zero
  __shared__ float sw2[H2 * OUT_F];  // [25][128]
  __shared__ float sb1[28];
  __shared__ float sb2[OUT_F];
  const int t = threadIdx.x;
  for (int i = t; i < ZF * 28; i += 64) {
    int k = i / 28, j = i % 28;
    sw1[i] = (j < H2) ? w1[k * H2 + j] : 0.0f;
  }
  for (int i = t; i < H2 * OUT_F; i += 64) sw2[i] = w2[i];
  if (t < 28) sb1[t] = (t < H2) ? b1[t] : 0.0f;
  for (int i = t; i < OUT_F; i += 64) sb2[i] = b2[i];
  __syncthreads();

  const int node = blockIdx.x * 64 + t;
  const float4* __restrict__ sw1v = (const float4*)sw1;
  const float4* __restrict__ sw2v = (const float4*)sw2;

  float g[28];
#pragma unroll
  for (int j = 0; j < 28; ++j) g[j] = sb1[j];

  const float4* __restrict__ nrow = (const float4*)(nodes + (size_t)node * IN_F);
#pragma unroll 2
  for (int k4 = 0; k4 < IN_F / 4; ++k4) {
    float4 x = nrow[k4];
    float xs[4] = {x.x, x.y, x.z, x.w};
#pragma unroll
    for (int kk = 0; kk < 4; ++kk) {
      const int k = k4 * 4 + kk;
#pragma unroll
      for (int j4 = 0; j4 < 7; ++j4) {
        float4 w = sw1v[k * 7 + j4];
        g[j4 * 4 + 0] = fmaf(xs[kk], w.x, g[j4 * 4 + 0]);
        g[j4 * 4 + 1] = fmaf(xs[kk], w.y, g[j4 * 4 + 1]);
        g[j4 * 4 + 2] = fmaf(xs[kk], w.z, g[j4 * 4 + 2]);
        g[j4 * 4 + 3] = fmaf(xs[kk], w.w, g[j4 * 4 + 3]);
      }
    }
  }

  const float invc = 1.0f / cnt[node];
  const float4* __restrict__ prow = (const float4*)(acc + (size_t)node * PSI_F);
#pragma unroll
  for (int k4 = 0; k4 < PSI_F / 4; ++k4) {
    float4 p = prow[k4];
    float xs[4] = {p.x * invc, p.y * invc, p.z * invc, p.w * invc};
#pragma unroll
    for (int kk = 0; kk < 4; ++kk) {
      const int k = IN_F + k4 * 4 + kk;
#pragma unroll
      for (int j4 = 0; j4 < 7; ++j4) {
        float4 w = sw1v[k * 7 + j4];
        g[j4 * 4 + 0] = fmaf(xs[kk], w.x, g[j4 * 4 + 0]);
        g[j4 * 4 + 1] = fmaf(xs[kk], w.y, g[j4 * 4 + 1]);
        g[j4 * 4 + 2] = fmaf(xs[kk], w.z, g[j4 * 4 + 2]);
        g[j4 * 4 + 3] = fmaf(xs[kk], w.w, g[j4 * 4 + 3]);
      }
    }
  }

#pragma unroll
  for (int j = 0; j < H2; ++j) g[j] = fmaxf(g[j], 0.0f);

  float4* __restrict__ op = (float4*)(out + (size_t)node * OUT_F);
#pragma unroll
  for (int oc = 0; oc < 4; ++oc) {
    float o[32];
#pragma unroll
    for (int i = 0; i < 32; ++i) o[i] = sb2[oc * 32 + i];
#pragma unroll
    for (int j = 0; j < H2; ++j) {
      float gv = g[j];
#pragma unroll
      for (int o4 = 0; o4 < 8; ++o4) {
        float4 w = sw2v[(j * OUT_F + oc * 32) / 4 + o4];
        o[o4 * 4 + 0] = fmaf(gv, w.x, o[o4 * 4 + 0]);
        o[o4 * 4 + 1] = fmaf(gv, w.y, o[o4 * 4 + 1]);
        o[o4 * 4 + 2] = fmaf(gv, w.z, o[o4 * 4 + 2]);
        o[o4 * 4 + 3] = fmaf(gv, w.w, o[o4 * 4 + 3]);
      }
    }
#pragma unroll
    for (int o4 = 0; o4 < 8; ++o4) {
      op[oc * 8 + o4] = make_float4(fmaxf(o[o4 * 4 + 0], 0.0f), fmaxf(o[o4 * 4 + 1], 0.0f),
                                    fmaxf(o[o4 * 4 + 2], 0.0f), fmaxf(o[o4 * 4 + 3], 0.0f));
    }
  }
}

extern "C" void kernel_launch(void* const* d_in, const int* in_sizes, int n_in,
                              void* d_out, int out_size, void* d_ws, size_t ws_size,
                              hipStream_t stream) {
  const float* nodes  = (const float*)d_in[0];
  const int*   A      = (const int*)d_in[1];
  const float* psi_w1 = (const float*)d_in[2];
  const float* psi_b1 = (const float*)d_in[3];
  const float* psi_w2 = (const float*)d_in[4];
  const float* psi_b2 = (const float*)d_in[5];
  const float* fi_w1  = (const float*)d_in[6];
  const float* fi_b1  = (const float*)d_in[7];
  const float* fi_w2  = (const float*)d_in[8];
  const float* fi_b2  = (const float*)d_in[9];
  float* out = (float*)d_out;

  // workspace layout (everything fully overwritten before read; no zeroing needed):
  // h    [N][16]            1 MB
  // pacc [RS][N][16]       64 MB
  // pcnt [RS][N]            4 MB
  // acc  [N][16]            1 MB
  // cnt  [N]               64 KB
  float* h    = (float*)d_ws;
  float* pacc = h + (size_t)N_NODES * PSI_F;
  float* pcnt = pacc + (size_t)AGG_RS * N_NODES * PSI_F;
  float* acc  = pcnt + (size_t)AGG_RS * N_NODES;
  float* cnt  = acc + (size_t)N_NODES * PSI_F;

  psi_kernel<<<N_NODES / 64, 64, 0, stream>>>(nodes, psi_w1, psi_b1, psi_w2, psi_b2, h);
  agg_kernel<<<AGG_CB * AGG_RS, AGG_TB, 0, stream>>>(A, h, pacc, pcnt);
  reduce_kernel<<<N_NODES * PSI_F / 256, 256, 0, stream>>>(pacc, pcnt, acc, cnt);
  fi_kernel<<<N_NODES / 64, 64, 0, stream>>>(nodes, acc, cnt, fi_w1, fi_b1, fi_w2, fi_b2, out);
}

// Round 3
// 1417.707 us; speedup vs baseline: 1.2736x; 1.0608x over previous
//
#include <hip/hip_runtime.h>

#define N_NODES 16384
#define IN_F    128
#define H1      15      // psi hidden (padded to 16 in LDS)
#define PSI_F   16
#define ZF      (IN_F + PSI_F)   // 144
#define H2      25      // fi hidden (padded to 28 in LDS)
#define OUT_F   128

// ---- agg kernel tiling ----
#define AGG_TB   256                 // threads per block
#define AGG_CPT  4                   // columns per thread (int4 load)
#define AGG_CPB  (AGG_TB * AGG_CPT)  // 1024 columns per block
#define AGG_CB   (N_NODES / AGG_CPB) // 16 column blocks
#define AGG_RS   32                  // row slices
#define AGG_RPB  (N_NODES / AGG_RS)  // 512 rows per block

typedef int   v4i __attribute__((ext_vector_type(4)));
typedef float v4f __attribute__((ext_vector_type(4)));

// ===================== psi MLP: h = relu(relu(x W1 + b1) W2 + b2) =====================
__global__ __launch_bounds__(64) void psi_kernel(
    const float* __restrict__ nodes,
    const float* __restrict__ w1, const float* __restrict__ b1,
    const float* __restrict__ w2, const float* __restrict__ b2,
    float* __restrict__ h) {
  __shared__ float sw1[IN_F * 16];   // [128][16], col 15 zero-padded
  __shared__ float sw2[16 * PSI_F];  // [16][16], row 15 zero-padded
  __shared__ float sb1[16];
  __shared__ float sb2[PSI_F];
  const int t = threadIdx.x;
  for (int i = t; i < IN_F * 16; i += 64) {
    int k = i >> 4, j = i & 15;
    sw1[i] = (j < H1) ? w1[k * H1 + j] : 0.0f;
  }
  for (int i = t; i < 16 * PSI_F; i += 64) {
    int j = i >> 4, j2 = i & 15;
    sw2[i] = (j < H1) ? w2[j * PSI_F + j2] : 0.0f;
  }
  if (t < 16)   sb1[t] = (t < H1) ? b1[t] : 0.0f;
  if (t < PSI_F) sb2[t] = b2[t];
  __syncthreads();

  const int node = blockIdx.x * 64 + t;
  const float4* __restrict__ row = (const float4*)(nodes + (size_t)node * IN_F);
  const float4* __restrict__ sw1v = (const float4*)sw1;
  const float4* __restrict__ sw2v = (const float4*)sw2;

  float a1[16];
#pragma unroll
  for (int j = 0; j < 16; ++j) a1[j] = sb1[j];

#pragma unroll 4
  for (int k4 = 0; k4 < IN_F / 4; ++k4) {
    float4 x = row[k4];
    float xs[4] = {x.x, x.y, x.z, x.w};
#pragma unroll
    for (int kk = 0; kk < 4; ++kk) {
#pragma unroll
      for (int j4 = 0; j4 < 4; ++j4) {
        float4 w = sw1v[(k4 * 4 + kk) * 4 + j4];
        a1[j4 * 4 + 0] = fmaf(xs[kk], w.x, a1[j4 * 4 + 0]);
        a1[j4 * 4 + 1] = fmaf(xs[kk], w.y, a1[j4 * 4 + 1]);
        a1[j4 * 4 + 2] = fmaf(xs[kk], w.z, a1[j4 * 4 + 2]);
        a1[j4 * 4 + 3] = fmaf(xs[kk], w.w, a1[j4 * 4 + 3]);
      }
    }
  }

  float a2[PSI_F];
#pragma unroll
  for (int j2 = 0; j2 < PSI_F; ++j2) a2[j2] = sb2[j2];
#pragma unroll
  for (int j = 0; j < 16; ++j) {
    float v = fmaxf(a1[j], 0.0f);   // row 15 of sw2 is zero, padded lane harmless
#pragma unroll
    for (int j4 = 0; j4 < 4; ++j4) {
      float4 w = sw2v[j * 4 + j4];
      a2[j4 * 4 + 0] = fmaf(v, w.x, a2[j4 * 4 + 0]);
      a2[j4 * 4 + 1] = fmaf(v, w.y, a2[j4 * 4 + 1]);
      a2[j4 * 4 + 2] = fmaf(v, w.z, a2[j4 * 4 + 2]);
      a2[j4 * 4 + 3] = fmaf(v, w.w, a2[j4 * 4 + 3]);
    }
  }

  float4* __restrict__ hp = (float4*)(h + (size_t)node * PSI_F);
#pragma unroll
  for (int j4 = 0; j4 < 4; ++j4) {
    hp[j4] = make_float4(fmaxf(a2[j4 * 4 + 0], 0.0f), fmaxf(a2[j4 * 4 + 1], 0.0f),
                         fmaxf(a2[j4 * 4 + 2], 0.0f), fmaxf(a2[j4 * 4 + 3], 0.0f));
  }
}

// ===================== aggregation partials =====================
// pacc[rs][c][k] = sum_{r in slice rs} A[r][c] * h[r][k]
// pcnt[rs][c]    = sum_{r in slice rs} A[r][c]
__global__ __launch_bounds__(256) void agg_kernel(
    const int* __restrict__ A, const float* __restrict__ h,
    float* __restrict__ pacc, float* __restrict__ pcnt) {
  __shared__ float sh[AGG_RPB * PSI_F];   // 32 KB: h slice for this block's rows
  const int cb = blockIdx.x % AGG_CB;
  const int rs = blockIdx.x / AGG_CB;
  const int r0 = rs * AGG_RPB;

  // stage h[r0 .. r0+511][0..15] into LDS
  {
    const float4* __restrict__ hsrc = (const float4*)(h + (size_t)r0 * PSI_F);
    float4* __restrict__ shv = (float4*)sh;
#pragma unroll
    for (int i = 0; i < AGG_RPB * PSI_F / 4 / AGG_TB; ++i)
      shv[i * AGG_TB + threadIdx.x] = hsrc[i * AGG_TB + threadIdx.x];
  }
  __syncthreads();

  const int c0 = cb * AGG_CPB + threadIdx.x * AGG_CPT;

  float s[AGG_CPT][PSI_F];
  float n[AGG_CPT];
#pragma unroll
  for (int c = 0; c < AGG_CPT; ++c) {
    n[c] = 0.0f;
#pragma unroll
    for (int k = 0; k < PSI_F; ++k) s[c][k] = 0.0f;
  }

  const v4i* __restrict__ ap = (const v4i*)(A + (size_t)r0 * N_NODES + c0);
  const float4* __restrict__ shv = (const float4*)sh;

#pragma unroll 8
  for (int r = 0; r < AGG_RPB; ++r) {
    v4i av = __builtin_nontemporal_load(ap);
    ap += N_NODES / 4;
    float a[AGG_CPT] = {(float)av[0], (float)av[1], (float)av[2], (float)av[3]};
    float4 hv[4] = {shv[r * 4 + 0], shv[r * 4 + 1], shv[r * 4 + 2], shv[r * 4 + 3]};
#pragma unroll
    for (int c = 0; c < AGG_CPT; ++c) {
#pragma unroll
      for (int q = 0; q < 4; ++q) {
        s[c][q * 4 + 0] = fmaf(a[c], hv[q].x, s[c][q * 4 + 0]);
        s[c][q * 4 + 1] = fmaf(a[c], hv[q].y, s[c][q * 4 + 1]);
        s[c][q * 4 + 2] = fmaf(a[c], hv[q].z, s[c][q * 4 + 2]);
        s[c][q * 4 + 3] = fmaf(a[c], hv[q].w, s[c][q * 4 + 3]);
      }
      n[c] += a[c];
    }
  }

  // write partials (contiguous 256 B per thread, coalesced across wave)
  float* __restrict__ pa = pacc + ((size_t)rs * N_NODES + c0) * PSI_F;
#pragma unroll
  for (int c = 0; c < AGG_CPT; ++c) {
#pragma unroll
    for (int q = 0; q < 4; ++q) {
      v4f v = {s[c][q * 4 + 0], s[c][q * 4 + 1], s[c][q * 4 + 2], s[c][q * 4 + 3]};
      __builtin_nontemporal_store(v, (v4f*)(pa + c * PSI_F + q * 4));
    }
  }
  v4f nv = {n[0], n[1], n[2], n[3]};
  __builtin_nontemporal_store(nv, (v4f*)(pcnt + (size_t)rs * N_NODES + c0));
}

// ===================== fi MLP (+ fused partial reduction) =====================
// psi_out[node][k] = (sum_rs pacc[rs][node][k]) / (sum_rs pcnt[rs][node])
// out = relu(relu([x, psi_out] W1 + b1) W2 + b2)
__global__ __launch_bounds__(64) void fi_kernel(
    const float* __restrict__ nodes,
    const float* __restrict__ pacc, const float* __restrict__ pcnt,
    const float* __restrict__ w1, const float* __restrict__ b1,
    const float* __restrict__ w2, const float* __restrict__ b2,
    float* __restrict__ out) {
  __shared__ float sw1[ZF * 28];     // [144][28], cols 25..27 zero
  __shared__ float sw2[H2 * OUT_F];  // [25][128]
  __shared__ float sb1[28];
  __shared__ float sb2[OUT_F];
  const int t = threadIdx.x;
  for (int i = t; i < ZF * 28; i += 64) {
    int k = i / 28, j = i % 28;
    sw1[i] = (j < H2) ? w1[k * H2 + j] : 0.0f;
  }
  for (int i = t; i < H2 * OUT_F; i += 64) sw2[i] = w2[i];
  if (t < 28) sb1[t] = (t < H2) ? b1[t] : 0.0f;
  for (int i = t; i < OUT_F; i += 64) sb2[i] = b2[i];
  __syncthreads();

  const int node = blockIdx.x * 64 + t;
  const float4* __restrict__ sw1v = (const float4*)sw1;
  const float4* __restrict__ sw2v = (const float4*)sw2;

  // ---- fused reduction of partials ----
  float ps[PSI_F];
#pragma unroll
  for (int k = 0; k < PSI_F; ++k) ps[k] = 0.0f;
  float cn = 0.0f;
#pragma unroll 4
  for (int rs = 0; rs < AGG_RS; ++rs) {
    const float4* __restrict__ pp =
        (const float4*)(pacc + ((size_t)rs * N_NODES + node) * PSI_F);
#pragma unroll
    for (int q = 0; q < 4; ++q) {
      float4 p = pp[q];
      ps[q * 4 + 0] += p.x; ps[q * 4 + 1] += p.y;
      ps[q * 4 + 2] += p.z; ps[q * 4 + 3] += p.w;
    }
    cn += pcnt[(size_t)rs * N_NODES + node];
  }
  const float invc = 1.0f / cn;

  float g[28];
#pragma unroll
  for (int j = 0; j < 28; ++j) g[j] = sb1[j];

  const float4* __restrict__ nrow = (const float4*)(nodes + (size_t)node * IN_F);
#pragma unroll 2
  for (int k4 = 0; k4 < IN_F / 4; ++k4) {
    float4 x = nrow[k4];
    float xs[4] = {x.x, x.y, x.z, x.w};
#pragma unroll
    for (int kk = 0; kk < 4; ++kk) {
      const int k = k4 * 4 + kk;
#pragma unroll
      for (int j4 = 0; j4 < 7; ++j4) {
        float4 w = sw1v[k * 7 + j4];
        g[j4 * 4 + 0] = fmaf(xs[kk], w.x, g[j4 * 4 + 0]);
        g[j4 * 4 + 1] = fmaf(xs[kk], w.y, g[j4 * 4 + 1]);
        g[j4 * 4 + 2] = fmaf(xs[kk], w.z, g[j4 * 4 + 2]);
        g[j4 * 4 + 3] = fmaf(xs[kk], w.w, g[j4 * 4 + 3]);
      }
    }
  }

#pragma unroll
  for (int kk = 0; kk < PSI_F; ++kk) {
    const float xv = ps[kk] * invc;
    const int k = IN_F + kk;
#pragma unroll
    for (int j4 = 0; j4 < 7; ++j4) {
      float4 w = sw1v[k * 7 + j4];
      g[j4 * 4 + 0] = fmaf(xv, w.x, g[j4 * 4 + 0]);
      g[j4 * 4 + 1] = fmaf(xv, w.y, g[j4 * 4 + 1]);
      g[j4 * 4 + 2] = fmaf(xv, w.z, g[j4 * 4 + 2]);
      g[j4 * 4 + 3] = fmaf(xv, w.w, g[j4 * 4 + 3]);
    }
  }

#pragma unroll
  for (int j = 0; j < H2; ++j) g[j] = fmaxf(g[j], 0.0f);

  float4* __restrict__ op = (float4*)(out + (size_t)node * OUT_F);
#pragma unroll
  for (int oc = 0; oc < 4; ++oc) {
    float o[32];
#pragma unroll
    for (int i = 0; i < 32; ++i) o[i] = sb2[oc * 32 + i];
#pragma unroll
    for (int j = 0; j < H2; ++j) {
      float gv = g[j];
#pragma unroll
      for (int o4 = 0; o4 < 8; ++o4) {
        float4 w = sw2v[(j * OUT_F + oc * 32) / 4 + o4];
        o[o4 * 4 + 0] = fmaf(gv, w.x, o[o4 * 4 + 0]);
        o[o4 * 4 + 1] = fmaf(gv, w.y, o[o4 * 4 + 1]);
        o[o4 * 4 + 2] = fmaf(gv, w.z, o[o4 * 4 + 2]);
        o[o4 * 4 + 3] = fmaf(gv, w.w, o[o4 * 4 + 3]);
      }
    }
#pragma unroll
    for (int o4 = 0; o4 < 8; ++o4) {
      op[oc * 8 + o4] = make_float4(fmaxf(o[o4 * 4 + 0], 0.0f), fmaxf(o[o4 * 4 + 1], 0.0f),
                                    fmaxf(o[o4 * 4 + 2], 0.0f), fmaxf(o[o4 * 4 + 3], 0.0f));
    }
  }
}

extern "C" void kernel_launch(void* const* d_in, const int* in_sizes, int n_in,
                              void* d_out, int out_size, void* d_ws, size_t ws_size,
                              hipStream_t stream) {
  const float* nodes  = (const float*)d_in[0];
  const int*   A      = (const int*)d_in[1];
  const float* psi_w1 = (const float*)d_in[2];
  const float* psi_b1 = (const float*)d_in[3];
  const float* psi_w2 = (const float*)d_in[4];
  const float* psi_b2 = (const float*)d_in[5];
  const float* fi_w1  = (const float*)d_in[6];
  const float* fi_b1  = (const float*)d_in[7];
  const float* fi_w2  = (const float*)d_in[8];
  const float* fi_b2  = (const float*)d_in[9];
  float* out = (float*)d_out;

  // workspace layout (everything fully overwritten before read; no zeroing needed):
  // h    [N][16]            1 MB
  // pacc [RS][N][16]       32 MB
  // pcnt [RS][N]            2 MB
  float* h    = (float*)d_ws;
  float* pacc = h + (size_t)N_NODES * PSI_F;
  float* pcnt = pacc + (size_t)AGG_RS * N_NODES * PSI_F;

  psi_kernel<<<N_NODES / 64, 64, 0, stream>>>(nodes, psi_w1, psi_b1, psi_w2, psi_b2, h);
  agg_kernel<<<AGG_CB * AGG_RS, AGG_TB, 0, stream>>>(A, h, pacc, pcnt);
  fi_kernel<<<N_NODES / 64, 64, 0, stream>>>(nodes, pacc, pcnt, fi_w1, fi_b1, fi_w2, fi_b2, out);
}